// Round 8
// baseline (185.293 us; speedup 1.0000x reference)
//
#include <hip/hip_runtime.h>
#include <hip/hip_bf16.h>

#define NN 512      // nodes per graph
#define NE 8192     // edges per graph
#define NG 128      // graphs (B*G)
#define FH 128      // feature/hidden dim
#define APITCH 68   // A f32 pitch: 272 B row, lane stride 4 banks -> 4-way read conflict (ok)
#define XPITCH 136
#define BN_EPS 1e-5f

typedef __attribute__((ext_vector_type(8))) short s8v;            // 8 bf16 = 4 VGPRs
typedef __attribute__((ext_vector_type(4))) float f4v;            // 16x16 MFMA C/D
typedef __attribute__((ext_vector_type(16))) float f16v;          // 32x32 MFMA C/D
typedef __attribute__((ext_vector_type(4))) unsigned short us4v;  // native ushort4
typedef __attribute__((ext_vector_type(4))) unsigned int u4v;

__device__ inline unsigned short f2bf(float x) {   // RNE fp32 -> bf16 bits
    unsigned u = __float_as_uint(x);
    unsigned r = (u + 0x7fffu + ((u >> 16) & 1u)) >> 16;
    return (unsigned short)r;
}
__device__ inline float bf2f(unsigned short h) { return __uint_as_float(((unsigned)h) << 16); }

// pack hi16(f1):hi16(f0) -> one u32 (exact bf16 for integer-valued floats < 256)
__device__ inline unsigned bfpack(int f1bits, int f0bits) {
    return __builtin_amdgcn_perm((unsigned)f1bits, (unsigned)f0bits, 0x07060302u);
}

// ---------------- K1: degrees + norms + 32-bucket (dst128blk, src64chunk) packed edges;
//                 payload = (d&127)<<6 | (s&63); blocks >= NG pack W ----------------
__global__ __launch_bounds__(1024) void k_build(const int* __restrict__ edges,
                                                float* __restrict__ rs_out,
                                                float* __restrict__ rs_in,
                                                int* __restrict__ bofs,
                                                unsigned short* __restrict__ epk,
                                                const float* __restrict__ W0,
                                                const float* __restrict__ W1,
                                                unsigned short* __restrict__ WP) {
    int g = blockIdx.x;
    int tid = threadIdx.x;

    if (g >= NG) {
        int which = g - NG;
        const float* W = which ? W1 : W0;
        for (int task = tid; task < 2048; task += 1024) {
            int t = task >> 6;            // 0..31  (nt*4+kk)
            int lane = task & 63;
            int nt = t >> 2, kk = t & 3;
            int n = nt * 16 + (lane & 15);
            int k0 = kk * 32 + (lane >> 4) * 8;
            unsigned short* dh = WP + ((size_t)which * 2 + 0) * 16384 + ((size_t)t * 64 + lane) * 8;
            unsigned short* dl = WP + ((size_t)which * 2 + 1) * 16384 + ((size_t)t * 64 + lane) * 8;
#pragma unroll
            for (int j = 0; j < 8; j++) {
                float v = W[(size_t)(k0 + j) * FH + n];
                unsigned short h = f2bf(v);
                dh[j] = h;
                dl[j] = f2bf(v - bf2f(h));
            }
        }
        return;
    }

    const int* src = edges + (size_t)g * 2 * NE;
    const int* dst = src + NE;

    __shared__ int degO[NN], degI[NN];
    __shared__ int scanA[1024], scanB[1024];   // [bucket 32][replica 32] counts / scan ping-pong
    __shared__ int fill[1024];
    __shared__ unsigned short pk[NE];          // 16 KB packed edges

    for (int i = tid; i < NN; i += 1024) { degO[i] = 0; degI[i] = 0; }
    scanA[tid] = 0;
    __syncthreads();

    int rep = tid & 31;
    for (int u = tid; u < NE / 4; u += 1024) {
        int4 s = ((const int4*)src)[u];
        int4 d = ((const int4*)dst)[u];
        atomicAdd(&degO[s.x], 1); atomicAdd(&degO[s.y], 1);
        atomicAdd(&degO[s.z], 1); atomicAdd(&degO[s.w], 1);
        atomicAdd(&degI[d.x], 1); atomicAdd(&degI[d.y], 1);
        atomicAdd(&degI[d.z], 1); atomicAdd(&degI[d.w], 1);
        atomicAdd(&scanA[((((d.x >> 7) << 3) | (s.x >> 6)) << 5) + rep], 1);
        atomicAdd(&scanA[((((d.y >> 7) << 3) | (s.y >> 6)) << 5) + rep], 1);
        atomicAdd(&scanA[((((d.z >> 7) << 3) | (s.z >> 6)) << 5) + rep], 1);
        atomicAdd(&scanA[((((d.w >> 7) << 3) | (s.w >> 6)) << 5) + rep], 1);
    }
    __syncthreads();

    for (int i = tid; i < NN; i += 1024) {
        rs_out[g * NN + i] = rsqrtf((float)max(degO[i], 1));
        rs_in [g * NN + i] = rsqrtf((float)max(degI[i], 1));
    }

    // inclusive Hillis-Steele scan over the 1024 (bucket,replica) cells
    int* sA = scanA; int* sB = scanB;
    for (int off = 1; off < 1024; off <<= 1) {
        int v = sA[tid];
        if (tid >= off) v += sA[tid - off];
        sB[tid] = v;
        __syncthreads();
        int* t = sA; sA = sB; sB = t;
    }
    int excl = tid ? sA[tid - 1] : 0;
    fill[tid] = excl;
    if ((tid & 31) == 0) bofs[g * 33 + (tid >> 5)] = excl;   // bucket start = excl at cell b*32
    if (tid == 0) bofs[g * 33 + 32] = NE;
    __syncthreads();

    for (int u = tid; u < NE / 4; u += 1024) {
        int4 s = ((const int4*)src)[u];
        int4 d = ((const int4*)dst)[u];
        int c, p;
        c = ((((d.x >> 7) << 3) | (s.x >> 6)) << 5) + rep;
        p = atomicAdd(&fill[c], 1); pk[p] = (unsigned short)(((d.x & 127) << 6) | (s.x & 63));
        c = ((((d.y >> 7) << 3) | (s.y >> 6)) << 5) + rep;
        p = atomicAdd(&fill[c], 1); pk[p] = (unsigned short)(((d.y & 127) << 6) | (s.y & 63));
        c = ((((d.z >> 7) << 3) | (s.z >> 6)) << 5) + rep;
        p = atomicAdd(&fill[c], 1); pk[p] = (unsigned short)(((d.z & 127) << 6) | (s.z & 63));
        c = ((((d.w >> 7) << 3) | (s.w >> 6)) << 5) + rep;
        p = atomicAdd(&fill[c], 1); pk[p] = (unsigned short)(((d.w & 127) << 6) | (s.w & 63));
    }
    __syncthreads();
    // 8192 ushorts = 1024 int4, exactly one per thread
    ((int4*)(epk + (size_t)g * NE))[tid] = ((const int4*)pk)[tid];
}

// ---------------- K1.5: densify A ONCE -> bf16 MFMA A-fragments in global ----------------
// frag addr (ushort units, per graph): (((Rg*32 + K)*2 + lh)*32 + l31)*8 + j
// holds A[Rg*32 + l31][K*16 + lh*8 + j]  (Rg = dst 32-row block, K = src 16-col block)
__global__ __launch_bounds__(512) void k_packA(const int* __restrict__ bofs,
                                               const unsigned short* __restrict__ epk,
                                               unsigned short* __restrict__ AP) {
    int g = blockIdx.x, sb = blockIdx.y, tid = threadIdx.x;
    __shared__ float Af[128 * APITCH];    // 34816 B
    __shared__ int bo_s[9];
    const unsigned short* ep = epk + (size_t)g * NE;
    unsigned short* Ag = AP + (size_t)g * 262144;

    if (tid < 9) bo_s[tid] = bofs[g * 33 + sb * 8 + tid];
    __syncthreads();
    int evNext = -1;
    { int e0 = bo_s[0] + tid; if (e0 < bo_s[1]) evNext = (int)ep[e0]; }

    for (int p = 0; p < 8; p++) {
        if (p) __syncthreads();          // prior pass's convert reads done
        float4 z4 = {0.f, 0.f, 0.f, 0.f};
        for (int i = tid; i < 128 * APITCH / 4; i += 512) ((float4*)Af)[i] = z4;
        __syncthreads();
        if (evNext >= 0) atomicAdd(&Af[(evNext >> 6) * APITCH + (evNext & 63)], 1.0f);
        for (int e = bo_s[p] + tid + 512; e < bo_s[p + 1]; e += 512) {   // practically never taken
            int v = ep[e];
            atomicAdd(&Af[(v >> 6) * APITCH + (v & 63)], 1.0f);
        }
        __syncthreads();
        if (p < 7) { int e1 = bo_s[p + 1] + tid; evNext = (e1 < bo_s[p + 2]) ? (int)ep[e1] : -1; }
        else evNext = -1;
        // convert + store: 1024 16B units (Rl,Kl,lh,l31), 2 per thread
#pragma unroll
        for (int uu = 0; uu < 2; uu++) {
            int u = tid + uu * 512;
            int l31 = u & 31, lh = (u >> 5) & 1, Kl = (u >> 6) & 3, Rl = (u >> 8) & 3;
            const int4* ap = (const int4*)&Af[(Rl * 32 + l31) * APITCH + Kl * 16 + lh * 8];
            int4 a0 = ap[0], a1 = ap[1];
            u4v cv;
            cv.x = bfpack(a0.y, a0.x);
            cv.y = bfpack(a0.w, a0.z);
            cv.z = bfpack(a1.y, a1.x);
            cv.w = bfpack(a1.w, a1.z);
            int Rg = sb * 4 + Rl, K = p * 4 + Kl;
            *(u4v*)(Ag + (((size_t)(Rg * 32 + K) * 2 + lh) * 32 + l31) * 8) = cv;
        }
    }
}

// ---------------- K2: Y1P = pack32((feats @ W0) * rs_out)  (hi/lo split, 3 MFMA) ----------------
// Y1P layout (per graph): idx = ((kb*2 + h)*128 + c)*8 + j holds Y[kb*16 + h*8 + j][c]
__global__ __launch_bounds__(256) void k_gemm_f32(const float* __restrict__ X,
                                                  const unsigned short* __restrict__ WPh,
                                                  const unsigned short* __restrict__ WPl,
                                                  const float* __restrict__ rs,
                                                  unsigned short* __restrict__ Yf) {
    __shared__ unsigned short xh[64 * XPITCH];   // 17 KB
    __shared__ unsigned short xl[64 * XPITCH];   // 17 KB
    int tid = threadIdx.x;
    int sb = blockIdx.y;
    size_t r0 = (size_t)blockIdx.x * NN + (size_t)sb * 64;

    const float4* Xv = (const float4*)(X + r0 * FH);
#pragma unroll
    for (int i = 0; i < 8; i++) {
        int u = tid + i * 256;                 // 2048 float4 = 64x128
        int row = u >> 5, c4 = (u & 31) * 4;
        float4 v = Xv[u];
        int off = row * XPITCH + c4;
        unsigned short h0 = f2bf(v.x), h1 = f2bf(v.y), h2 = f2bf(v.z), h3 = f2bf(v.w);
        us4v hv, lv;
        hv.x = h0; hv.y = h1; hv.z = h2; hv.w = h3;
        lv.x = f2bf(v.x - bf2f(h0));
        lv.y = f2bf(v.y - bf2f(h1));
        lv.z = f2bf(v.z - bf2f(h2));
        lv.w = f2bf(v.w - bf2f(h3));
        *(us4v*)(xh + off) = hv;
        *(us4v*)(xl + off) = lv;
    }
    __syncthreads();

    int lane = tid & 63, w = tid >> 6;
    int quad = lane >> 4, m = lane & 15;
    int arow = w * 16 + m;

    f4v acc[8];
#pragma unroll
    for (int nt = 0; nt < 8; nt++) acc[nt] = (f4v){0.f, 0.f, 0.f, 0.f};

#pragma unroll
    for (int kk = 0; kk < 4; kk++) {
        s8v ah = *(const s8v*)&xh[arow * XPITCH + kk * 32 + quad * 8];
        s8v al = *(const s8v*)&xl[arow * XPITCH + kk * 32 + quad * 8];
#pragma unroll
        for (int nt = 0; nt < 8; nt++) {
            s8v bh = *(const s8v*)(WPh + ((size_t)(nt * 4 + kk) * 64 + lane) * 8);
            s8v bl = *(const s8v*)(WPl + ((size_t)(nt * 4 + kk) * 64 + lane) * 8);
            acc[nt] = __builtin_amdgcn_mfma_f32_16x16x32_bf16(ah, bh, acc[nt], 0, 0, 0);
            acc[nt] = __builtin_amdgcn_mfma_f32_16x16x32_bf16(al, bh, acc[nt], 0, 0, 0);
            acc[nt] = __builtin_amdgcn_mfma_f32_16x16x32_bf16(ah, bl, acc[nt], 0, 0, 0);
        }
    }

    int orow = w * 16 + quad * 4;
    float4 rsv = *(const float4*)(rs + r0 + orow);
    // node n = sb*64 + w*16 + quad*4 + i -> kb = sb*4 + w, h = quad>>1, j = (quad&1)*4 + i
    int kb = sb * 4 + w, h2 = quad >> 1, j0 = (quad & 1) * 4;
    unsigned short* of = Yf + (size_t)blockIdx.x * (NN * FH);
#pragma unroll
    for (int nt = 0; nt < 8; nt++) {
        us4v v;
        v.x = f2bf(acc[nt][0] * rsv.x);
        v.y = f2bf(acc[nt][1] * rsv.y);
        v.z = f2bf(acc[nt][2] * rsv.z);
        v.w = f2bf(acc[nt][3] * rsv.w);
        *(us4v*)(of + ((size_t)(kb * 2 + h2) * 128 + nt * 16 + m) * 8 + j0) = v;
    }
}

// ---------------- K3: barrier-free fragment GEMM (A-frags x Y1-frags) + gemm2 -> Y2P ----------------
__global__ __launch_bounds__(512) void k_fused(const unsigned short* __restrict__ Y1f,
                                               const unsigned short* __restrict__ AP,
                                               const float* __restrict__ rs_in,
                                               const float* __restrict__ rs_out,
                                               const float* __restrict__ bias,
                                               const unsigned short* __restrict__ WPh,
                                               const unsigned short* __restrict__ WPl,
                                               unsigned short* __restrict__ Y2f) {
    int g  = blockIdx.x;
    int sb = blockIdx.y;   // 0..3
    int tid = threadIdx.x;
    int lane = tid & 63, w8 = tid >> 6;    // 8 waves
    int l31 = lane & 31, lh = lane >> 5;
    int mt = w8 & 3, nh = w8 >> 2;         // wave tile: rows mt*32..+31, cols nh*64..+63
    int base = sb * 128;

    __shared__ unsigned short hs[128 * XPITCH];  // 34816 B (agg result, then gemm2 A)
    __shared__ float rsin_s[128];

    if (tid < 128) rsin_s[tid] = rs_in[g * NN + base + tid];
    __syncthreads();

    const unsigned short* Yg = Y1f + (size_t)g * (NN * FH);
    const unsigned short* Ag = AP + (size_t)g * 262144;
    int Rg = sb * 4 + mt;
    int aoff  = Rg * 16384 + lh * 256 + l31 * 8;
    int boff0 = lh * 1024 + (nh * 64 + l31) * 8;
    int boff1 = boff0 + 256;

    f16v acc32[2];
#pragma unroll
    for (int t = 0; t < 2; t++)
#pragma unroll
        for (int i = 0; i < 16; i++) acc32[t][i] = 0.f;

    s8v aF[2][2], b0F[2][2], b1F[2][2];
    auto LD = [&](int buf, int Kb) {
#pragma unroll
        for (int q = 0; q < 2; q++) {
            int K = Kb + q;
            aF[buf][q]  = *(const s8v*)(Ag + aoff  + K * 512);
            b0F[buf][q] = *(const s8v*)(Yg + boff0 + K * 2048);
            b1F[buf][q] = *(const s8v*)(Yg + boff1 + K * 2048);
        }
    };
    LD(0, 0);
#pragma unroll
    for (int gq = 0; gq < 16; gq++) {
        int cur = gq & 1;
        if (gq < 15) LD(cur ^ 1, (gq + 1) * 2);
#pragma unroll
        for (int q = 0; q < 2; q++) {
            acc32[0] = __builtin_amdgcn_mfma_f32_32x32x16_bf16(aF[cur][q], b0F[cur][q], acc32[0], 0, 0, 0);
            acc32[1] = __builtin_amdgcn_mfma_f32_32x32x16_bf16(aF[cur][q], b1F[cur][q], acc32[1], 0, 0, 0);
        }
    }

    // ---- conv1 epilogue: h = relu(rs_in*agg + b0) -> hs (natural [row][feat]) ----
    // C layout (m74): col = lane&31, row = (reg&3) + 8*(reg>>2) + 4*(lane>>5)
#pragma unroll
    for (int t = 0; t < 2; t++) {
        int c = nh * 64 + t * 32 + l31;
        float bv = bias[c];
#pragma unroll
        for (int r = 0; r < 16; r++) {
            int row = mt * 32 + (r & 3) + 8 * (r >> 2) + 4 * lh;
            float hv = fmaxf(fmaf(rsin_s[row], acc32[t][r], bv), 0.f);
            hs[row * XPITCH + c] = f2bf(hv);
        }
    }
    __syncthreads();

    // ---- gemm2: Y2 = (h @ W1) * rs_out -> Y2P (pack32) ----
    int quad = lane >> 4, m16 = lane & 15;
    f4v acc2[8];
#pragma unroll
    for (int nt = 0; nt < 8; nt++) acc2[nt] = (f4v){0.f, 0.f, 0.f, 0.f};

#pragma unroll
    for (int kk = 0; kk < 4; kk++) {
        s8v ah = *(const s8v*)&hs[(w8 * 16 + m16) * XPITCH + kk * 32 + quad * 8];
#pragma unroll
        for (int nt = 0; nt < 8; nt++) {
            s8v bh = *(const s8v*)(WPh + ((size_t)(nt * 4 + kk) * 64 + lane) * 8);
            s8v bl = *(const s8v*)(WPl + ((size_t)(nt * 4 + kk) * 64 + lane) * 8);
            acc2[nt] = __builtin_amdgcn_mfma_f32_16x16x32_bf16(ah, bh, acc2[nt], 0, 0, 0);
            acc2[nt] = __builtin_amdgcn_mfma_f32_16x16x32_bf16(ah, bl, acc2[nt], 0, 0, 0);
        }
    }

    int orow = w8 * 16 + quad * 4;
    float4 rsv = *(const float4*)(rs_out + (size_t)g * NN + base + orow);
    int kb = sb * 8 + w8, h2 = quad >> 1, j0 = (quad & 1) * 4;
    unsigned short* of = Y2f + (size_t)g * (NN * FH);
#pragma unroll
    for (int nt = 0; nt < 8; nt++) {
        us4v v;
        v.x = f2bf(acc2[nt][0] * rsv.x);
        v.y = f2bf(acc2[nt][1] * rsv.y);
        v.z = f2bf(acc2[nt][2] * rsv.z);
        v.w = f2bf(acc2[nt][3] * rsv.w);
        *(us4v*)(of + ((size_t)(kb * 2 + h2) * 128 + nt * 16 + m16) * 8 + j0) = v;
    }
}

// ---------------- K4: barrier-free fragment GEMM (A-frags x Y2-frags) + relu + node-sum -> partial ----------------
__global__ __launch_bounds__(512) void k_gather_mean(const unsigned short* __restrict__ Y2f,
                                                     const unsigned short* __restrict__ AP,
                                                     const float* __restrict__ rs_in,
                                                     const float* __restrict__ bias,
                                                     float* __restrict__ partial) {
    int g  = blockIdx.x;
    int sb = blockIdx.y;   // 0..3
    int tid = threadIdx.x;
    int lane = tid & 63, w8 = tid >> 6;
    int l31 = lane & 31, lh = lane >> 5;
    int mt = w8 & 3, nh = w8 >> 2;
    int base = sb * 128;

    __shared__ float red[8 * 2 * 64];   // 4 KB
    __shared__ float rsin_s[128];

    if (tid < 128) rsin_s[tid] = rs_in[g * NN + base + tid];
    __syncthreads();

    const unsigned short* Yg = Y2f + (size_t)g * (NN * FH);
    const unsigned short* Ag = AP + (size_t)g * 262144;
    int Rg = sb * 4 + mt;
    int aoff  = Rg * 16384 + lh * 256 + l31 * 8;
    int boff0 = lh * 1024 + (nh * 64 + l31) * 8;
    int boff1 = boff0 + 256;

    f16v acc32[2];
#pragma unroll
    for (int t = 0; t < 2; t++)
#pragma unroll
        for (int i = 0; i < 16; i++) acc32[t][i] = 0.f;

    s8v aF[2][2], b0F[2][2], b1F[2][2];
    auto LD = [&](int buf, int Kb) {
#pragma unroll
        for (int q = 0; q < 2; q++) {
            int K = Kb + q;
            aF[buf][q]  = *(const s8v*)(Ag + aoff  + K * 512);
            b0F[buf][q] = *(const s8v*)(Yg + boff0 + K * 2048);
            b1F[buf][q] = *(const s8v*)(Yg + boff1 + K * 2048);
        }
    };
    LD(0, 0);
#pragma unroll
    for (int gq = 0; gq < 16; gq++) {
        int cur = gq & 1;
        if (gq < 15) LD(cur ^ 1, (gq + 1) * 2);
#pragma unroll
        for (int q = 0; q < 2; q++) {
            acc32[0] = __builtin_amdgcn_mfma_f32_32x32x16_bf16(aF[cur][q], b0F[cur][q], acc32[0], 0, 0, 0);
            acc32[1] = __builtin_amdgcn_mfma_f32_32x32x16_bf16(aF[cur][q], b1F[cur][q], acc32[1], 0, 0, 0);
        }
    }

    // ---- epilogue: relu(rs_in*agg + b1) summed over this lane's rows, per col ----
#pragma unroll
    for (int t = 0; t < 2; t++) {
        int c = nh * 64 + t * 32 + l31;
        float bv = bias[c];
        float s = 0.f;
#pragma unroll
        for (int r = 0; r < 16; r++) {
            int row = mt * 32 + (r & 3) + 8 * (r >> 2) + 4 * lh;
            s += fmaxf(fmaf(rsin_s[row], acc32[t][r], bv), 0.f);
        }
        red[(w8 * 2 + t) * 64 + lane] = s;
    }
    __syncthreads();
    if (tid < FH) {
        int f = tid;
        int nh2 = f >> 6, t2 = (f >> 5) & 1, cl = f & 31;
        float t = 0.f;
#pragma unroll
        for (int mtt = 0; mtt < 4; mtt++) {
            int w = nh2 * 4 + mtt;
            t += red[(w * 2 + t2) * 64 + cl] + red[(w * 2 + t2) * 64 + cl + 32];
        }
        partial[((size_t)g * 4 + sb) * FH + f] = t;
    }
}

// ---------------- K5: z = (sum partials)/512 @ Wt + bt; BN eval; relu ----------------
__global__ __launch_bounds__(128) void k_head(const float* __restrict__ partial,
                                              const float* __restrict__ Wt,
                                              const float* __restrict__ bt,
                                              const float* __restrict__ gamma,
                                              const float* __restrict__ beta,
                                              const float* __restrict__ rmean,
                                              const float* __restrict__ rvar,
                                              float* __restrict__ out) {
    int g = blockIdx.x;
    int j = threadIdx.x;
    __shared__ float e[FH];
    float acc4 = 0.f;
#pragma unroll
    for (int q = 0; q < 4; q++) acc4 += partial[((size_t)g * 4 + q) * FH + j];
    e[j] = acc4 * (1.0f / (float)NN);
    __syncthreads();
    float acc = bt[j];
#pragma unroll 8
    for (int k = 0; k < FH; k++) acc += e[k] * Wt[(size_t)k * FH + j];
    float z = gamma[j] * (acc - rmean[j]) * rsqrtf(rvar[j] + BN_EPS) + beta[j];
    out[g * FH + j] = fmaxf(z, 0.f);
}

extern "C" void kernel_launch(void* const* d_in, const int* in_sizes, int n_in,
                              void* d_out, int out_size, void* d_ws, size_t ws_size,
                              hipStream_t stream) {
    const float* feats = (const float*)d_in[0];
    const int*   edges = (const int*)d_in[1];
    const float* W0    = (const float*)d_in[2];
    const float* b0    = (const float*)d_in[3];
    const float* W1    = (const float*)d_in[4];
    const float* b1    = (const float*)d_in[5];
    const float* Wt    = (const float*)d_in[6];
    const float* bt    = (const float*)d_in[7];
    const float* gamma = (const float*)d_in[8];
    const float* beta  = (const float*)d_in[9];
    const float* rmean = (const float*)d_in[10];
    const float* rvar  = (const float*)d_in[11];
    float* out = (float*)d_out;

    // workspace layout
    char* w = (char*)d_ws;
    float* rs_out  = (float*)w;   w += sizeof(float) * NG * NN;
    float* rs_in   = (float*)w;   w += sizeof(float) * NG * NN;
    int*   bofs    = (int*)w;     w += sizeof(int) * NG * 33;              // 16896 B (16B multiple)
    unsigned short* epk = (unsigned short*)w; w += sizeof(unsigned short) * (size_t)NG * NE; // 2 MB
    unsigned short* WP  = (unsigned short*)w; w += sizeof(unsigned short) * 4 * 16384;       // 128 KB
    unsigned short* Y1  = (unsigned short*)w; w += sizeof(unsigned short) * (size_t)NG * NN * FH; // 16 MB
    unsigned short* Y2  = (unsigned short*)w; w += sizeof(unsigned short) * (size_t)NG * NN * FH; // 16 MB
    unsigned short* AP  = (unsigned short*)w; w += sizeof(unsigned short) * (size_t)NG * 262144; // 64 MB
    float* partial = (float*)w;   w += sizeof(float) * NG * 4 * FH;

    unsigned short* WPh0 = WP;
    unsigned short* WPl0 = WP + 16384;
    unsigned short* WPh1 = WP + 32768;
    unsigned short* WPl1 = WP + 49152;

    // K1: norms + bucketed packed edges; 2 extra blocks pack W0/W1
    k_build<<<NG + 2, 1024, 0, stream>>>(edges, rs_out, rs_in, bofs, epk, W0, W1, WP);

    // K1.5: densify A once -> bf16 MFMA fragments
    k_packA<<<dim3(NG, 4), 512, 0, stream>>>(bofs, epk, AP);

    // K2: conv1 gemm (feats -> Y1, pack32 format)
    k_gemm_f32<<<dim3(NG, 8), 256, 0, stream>>>(feats, WPh0, WPl0, rs_out, Y1);

    // K3: fragment GEMM agg + conv2 gemm (Y1 -> Y2, pack32)
    k_fused<<<dim3(NG, 4), 512, 0, stream>>>(Y1, AP, rs_in, rs_out, b0, WPh1, WPl1, Y2);

    // K4: fragment GEMM agg (conv2) + node-mean -> partial
    k_gather_mean<<<dim3(NG, 4), 512, 0, stream>>>(Y2, AP, rs_in, b1, partial);

    // K5: head
    k_head<<<NG, 128, 0, stream>>>(partial, Wt, bt, gamma, beta, rmean, rvar, out);

    (void)in_sizes; (void)n_in; (void)out_size; (void)ws_size;
}

// Round 9
// 180.413 us; speedup vs baseline: 1.0270x; 1.0270x over previous
//
#include <hip/hip_runtime.h>
#include <hip/hip_bf16.h>

#define NN 512      // nodes per graph
#define NE 8192     // edges per graph
#define NG 128      // graphs (B*G)
#define FH 128      // feature/hidden dim
#define APITCH 68   // A f32 pitch in packA scratch
#define XPITCH 136
#define BN_EPS 1e-5f

typedef __attribute__((ext_vector_type(8))) short s8v;            // 8 bf16 = 4 VGPRs
typedef __attribute__((ext_vector_type(4))) float f4v;            // 16x16 MFMA C/D
typedef __attribute__((ext_vector_type(16))) float f16v;          // 32x32 MFMA C/D
typedef __attribute__((ext_vector_type(4))) unsigned short us4v;  // native ushort4
typedef __attribute__((ext_vector_type(4))) unsigned int u4v;

__device__ inline unsigned short f2bf(float x) {   // RNE fp32 -> bf16 bits
    unsigned u = __float_as_uint(x);
    unsigned r = (u + 0x7fffu + ((u >> 16) & 1u)) >> 16;
    return (unsigned short)r;
}
__device__ inline float bf2f(unsigned short h) { return __uint_as_float(((unsigned)h) << 16); }

// pack hi16(f1):hi16(f0) -> one u32 (exact bf16 for integer-valued floats < 256)
__device__ inline unsigned bfpack(int f1bits, int f0bits) {
    return __builtin_amdgcn_perm((unsigned)f1bits, (unsigned)f0bits, 0x07060302u);
}

// ---------------- K1: degrees + norms + 32-bucket packed edges; extra blocks pack W ----------------
// block NG+0: W0 in 16x16 B-frag format (for K2); block NG+1: W1 in 32x32 B-frag format (for gemm2)
__global__ __launch_bounds__(1024) void k_build(const int* __restrict__ edges,
                                                float* __restrict__ rs_out,
                                                float* __restrict__ rs_in,
                                                int* __restrict__ bofs,
                                                unsigned short* __restrict__ epk,
                                                const float* __restrict__ W0,
                                                const float* __restrict__ W1,
                                                unsigned short* __restrict__ WP) {
    int g = blockIdx.x;
    int tid = threadIdx.x;

    if (g >= NG) {
        int which = g - NG;
        if (which == 0) {
            // W0 -> 16x16 B-frag (WPh0 | WPl0)
            for (int task = tid; task < 2048; task += 1024) {
                int t = task >> 6;            // 0..31  (nt*4+kk)
                int lane = task & 63;
                int nt = t >> 2, kk = t & 3;
                int n = nt * 16 + (lane & 15);
                int k0 = kk * 32 + (lane >> 4) * 8;
                unsigned short* dh = WP + ((size_t)t * 64 + lane) * 8;
                unsigned short* dl = WP + 16384 + ((size_t)t * 64 + lane) * 8;
#pragma unroll
                for (int j = 0; j < 8; j++) {
                    float v = W0[(size_t)(k0 + j) * FH + n];
                    unsigned short h = f2bf(v);
                    dh[j] = h;
                    dl[j] = f2bf(v - bf2f(h));
                }
            }
        } else {
            // W1 -> 32x32 B-frag: ((kk*2+lh)*128 + c)*8 + j holds W1[kk*16 + lh*8 + j][c]
            for (int task = tid; task < 2048; task += 1024) {
                int kk = task >> 8;           // 0..7
                int rem = task & 255;
                int lhp = rem >> 7, c = rem & 127;
                unsigned short* dh = WP + 2 * 16384 + ((size_t)((kk * 2 + lhp) * 128 + c)) * 8;
                unsigned short* dl = WP + 3 * 16384 + ((size_t)((kk * 2 + lhp) * 128 + c)) * 8;
#pragma unroll
                for (int j = 0; j < 8; j++) {
                    float v = W1[(size_t)(kk * 16 + lhp * 8 + j) * FH + c];
                    unsigned short h = f2bf(v);
                    dh[j] = h;
                    dl[j] = f2bf(v - bf2f(h));
                }
            }
        }
        return;
    }

    const int* src = edges + (size_t)g * 2 * NE;
    const int* dst = src + NE;

    __shared__ int degO[NN], degI[NN];
    __shared__ int scanA[1024], scanB[1024];   // [bucket 32][replica 32]
    __shared__ int fill[1024];
    __shared__ unsigned short pk[NE];          // 16 KB packed edges

    for (int i = tid; i < NN; i += 1024) { degO[i] = 0; degI[i] = 0; }
    scanA[tid] = 0;
    __syncthreads();

    int rep = tid & 31;
    for (int u = tid; u < NE / 4; u += 1024) {
        int4 s = ((const int4*)src)[u];
        int4 d = ((const int4*)dst)[u];
        atomicAdd(&degO[s.x], 1); atomicAdd(&degO[s.y], 1);
        atomicAdd(&degO[s.z], 1); atomicAdd(&degO[s.w], 1);
        atomicAdd(&degI[d.x], 1); atomicAdd(&degI[d.y], 1);
        atomicAdd(&degI[d.z], 1); atomicAdd(&degI[d.w], 1);
        atomicAdd(&scanA[((((d.x >> 7) << 3) | (s.x >> 6)) << 5) + rep], 1);
        atomicAdd(&scanA[((((d.y >> 7) << 3) | (s.y >> 6)) << 5) + rep], 1);
        atomicAdd(&scanA[((((d.z >> 7) << 3) | (s.z >> 6)) << 5) + rep], 1);
        atomicAdd(&scanA[((((d.w >> 7) << 3) | (s.w >> 6)) << 5) + rep], 1);
    }
    __syncthreads();

    for (int i = tid; i < NN; i += 1024) {
        rs_out[g * NN + i] = rsqrtf((float)max(degO[i], 1));
        rs_in [g * NN + i] = rsqrtf((float)max(degI[i], 1));
    }

    int* sA = scanA; int* sB = scanB;
    for (int off = 1; off < 1024; off <<= 1) {
        int v = sA[tid];
        if (tid >= off) v += sA[tid - off];
        sB[tid] = v;
        __syncthreads();
        int* t = sA; sA = sB; sB = t;
    }
    int excl = tid ? sA[tid - 1] : 0;
    fill[tid] = excl;
    if ((tid & 31) == 0) bofs[g * 33 + (tid >> 5)] = excl;
    if (tid == 0) bofs[g * 33 + 32] = NE;
    __syncthreads();

    for (int u = tid; u < NE / 4; u += 1024) {
        int4 s = ((const int4*)src)[u];
        int4 d = ((const int4*)dst)[u];
        int c, p;
        c = ((((d.x >> 7) << 3) | (s.x >> 6)) << 5) + rep;
        p = atomicAdd(&fill[c], 1); pk[p] = (unsigned short)(((d.x & 127) << 6) | (s.x & 63));
        c = ((((d.y >> 7) << 3) | (s.y >> 6)) << 5) + rep;
        p = atomicAdd(&fill[c], 1); pk[p] = (unsigned short)(((d.y & 127) << 6) | (s.y & 63));
        c = ((((d.z >> 7) << 3) | (s.z >> 6)) << 5) + rep;
        p = atomicAdd(&fill[c], 1); pk[p] = (unsigned short)(((d.z & 127) << 6) | (s.z & 63));
        c = ((((d.w >> 7) << 3) | (s.w >> 6)) << 5) + rep;
        p = atomicAdd(&fill[c], 1); pk[p] = (unsigned short)(((d.w & 127) << 6) | (s.w & 63));
    }
    __syncthreads();
    ((int4*)(epk + (size_t)g * NE))[tid] = ((const int4*)pk)[tid];
}

// ---------------- K1.5: densify A ONCE -> bf16 MFMA A-fragments in global ----------------
// frag addr (ushort units, per graph): (((Rg*32 + K)*2 + lh)*32 + l31)*8 + j
// holds A[Rg*32 + l31][K*16 + lh*8 + j]
__global__ __launch_bounds__(512) void k_packA(const int* __restrict__ bofs,
                                               const unsigned short* __restrict__ epk,
                                               unsigned short* __restrict__ AP) {
    int g = blockIdx.x, sb = blockIdx.y, tid = threadIdx.x;
    __shared__ float Af[128 * APITCH];    // 34816 B
    __shared__ int bo_s[9];
    const unsigned short* ep = epk + (size_t)g * NE;
    unsigned short* Ag = AP + (size_t)g * 262144;

    if (tid < 9) bo_s[tid] = bofs[g * 33 + sb * 8 + tid];
    __syncthreads();
    int evNext = -1;
    { int e0 = bo_s[0] + tid; if (e0 < bo_s[1]) evNext = (int)ep[e0]; }

    for (int p = 0; p < 8; p++) {
        if (p) __syncthreads();
        float4 z4 = {0.f, 0.f, 0.f, 0.f};
        for (int i = tid; i < 128 * APITCH / 4; i += 512) ((float4*)Af)[i] = z4;
        __syncthreads();
        if (evNext >= 0) atomicAdd(&Af[(evNext >> 6) * APITCH + (evNext & 63)], 1.0f);
        for (int e = bo_s[p] + tid + 512; e < bo_s[p + 1]; e += 512) {
            int v = ep[e];
            atomicAdd(&Af[(v >> 6) * APITCH + (v & 63)], 1.0f);
        }
        __syncthreads();
        if (p < 7) { int e1 = bo_s[p + 1] + tid; evNext = (e1 < bo_s[p + 2]) ? (int)ep[e1] : -1; }
        else evNext = -1;
#pragma unroll
        for (int uu = 0; uu < 2; uu++) {
            int u = tid + uu * 512;
            int l31 = u & 31, lh = (u >> 5) & 1, Kl = (u >> 6) & 3, Rl = (u >> 8) & 3;
            const int4* ap = (const int4*)&Af[(Rl * 32 + l31) * APITCH + Kl * 16 + lh * 8];
            int4 a0 = ap[0], a1 = ap[1];
            u4v cv;
            cv.x = bfpack(a0.y, a0.x);
            cv.y = bfpack(a0.w, a0.z);
            cv.z = bfpack(a1.y, a1.x);
            cv.w = bfpack(a1.w, a1.z);
            int Rg = sb * 4 + Rl, K = p * 4 + Kl;
            *(u4v*)(Ag + (((size_t)(Rg * 32 + K) * 2 + lh) * 32 + l31) * 8) = cv;
        }
    }
}

// ---------------- K2: Y1P = pack32((feats @ W0) * rs_out)  (hi/lo split, 3 MFMA) ----------------
__global__ __launch_bounds__(256) void k_gemm_f32(const float* __restrict__ X,
                                                  const unsigned short* __restrict__ WPh,
                                                  const unsigned short* __restrict__ WPl,
                                                  const float* __restrict__ rs,
                                                  unsigned short* __restrict__ Yf) {
    __shared__ unsigned short xh[64 * XPITCH];   // 17 KB
    __shared__ unsigned short xl[64 * XPITCH];   // 17 KB
    int tid = threadIdx.x;
    int sb = blockIdx.y;
    size_t r0 = (size_t)blockIdx.x * NN + (size_t)sb * 64;

    const float4* Xv = (const float4*)(X + r0 * FH);
#pragma unroll
    for (int i = 0; i < 8; i++) {
        int u = tid + i * 256;                 // 2048 float4 = 64x128
        int row = u >> 5, c4 = (u & 31) * 4;
        float4 v = Xv[u];
        int off = row * XPITCH + c4;
        unsigned short h0 = f2bf(v.x), h1 = f2bf(v.y), h2 = f2bf(v.z), h3 = f2bf(v.w);
        us4v hv, lv;
        hv.x = h0; hv.y = h1; hv.z = h2; hv.w = h3;
        lv.x = f2bf(v.x - bf2f(h0));
        lv.y = f2bf(v.y - bf2f(h1));
        lv.z = f2bf(v.z - bf2f(h2));
        lv.w = f2bf(v.w - bf2f(h3));
        *(us4v*)(xh + off) = hv;
        *(us4v*)(xl + off) = lv;
    }
    __syncthreads();

    int lane = tid & 63, w = tid >> 6;
    int quad = lane >> 4, m = lane & 15;
    int arow = w * 16 + m;

    f4v acc[8];
#pragma unroll
    for (int nt = 0; nt < 8; nt++) acc[nt] = (f4v){0.f, 0.f, 0.f, 0.f};

#pragma unroll
    for (int kk = 0; kk < 4; kk++) {
        s8v ah = *(const s8v*)&xh[arow * XPITCH + kk * 32 + quad * 8];
        s8v al = *(const s8v*)&xl[arow * XPITCH + kk * 32 + quad * 8];
#pragma unroll
        for (int nt = 0; nt < 8; nt++) {
            s8v bh = *(const s8v*)(WPh + ((size_t)(nt * 4 + kk) * 64 + lane) * 8);
            s8v bl = *(const s8v*)(WPl + ((size_t)(nt * 4 + kk) * 64 + lane) * 8);
            acc[nt] = __builtin_amdgcn_mfma_f32_16x16x32_bf16(ah, bh, acc[nt], 0, 0, 0);
            acc[nt] = __builtin_amdgcn_mfma_f32_16x16x32_bf16(al, bh, acc[nt], 0, 0, 0);
            acc[nt] = __builtin_amdgcn_mfma_f32_16x16x32_bf16(ah, bl, acc[nt], 0, 0, 0);
        }
    }

    int orow = w * 16 + quad * 4;
    float4 rsv = *(const float4*)(rs + r0 + orow);
    int kb = sb * 4 + w, h2 = quad >> 1, j0 = (quad & 1) * 4;
    unsigned short* of = Yf + (size_t)blockIdx.x * (NN * FH);
#pragma unroll
    for (int nt = 0; nt < 8; nt++) {
        us4v v;
        v.x = f2bf(acc[nt][0] * rsv.x);
        v.y = f2bf(acc[nt][1] * rsv.y);
        v.z = f2bf(acc[nt][2] * rsv.z);
        v.w = f2bf(acc[nt][3] * rsv.w);
        *(us4v*)(of + ((size_t)(kb * 2 + h2) * 128 + nt * 16 + m) * 8 + j0) = v;
    }
}

// ---------------- K3: 64x64/wave fragment GEMM agg (6-deep pipeline) + gemm2-32 -> Y2P ----------------
// 256 thr = 4 waves: wave (nh = w>>1 col-half, mq = w&1 row-pair); per K-step 4 loads : 4 MFMA.
__global__ __launch_bounds__(256, 2) void k_fused(const unsigned short* __restrict__ Y1f,
                                                  const unsigned short* __restrict__ AP,
                                                  const float* __restrict__ rs_in,
                                                  const float* __restrict__ rs_out,
                                                  const float* __restrict__ bias,
                                                  const unsigned short* __restrict__ W32h,
                                                  const unsigned short* __restrict__ W32l,
                                                  unsigned short* __restrict__ Y2f) {
    int g  = blockIdx.x;
    int sb = blockIdx.y;   // 0..3
    int tid = threadIdx.x;
    int lane = tid & 63, w4 = tid >> 6;    // 4 waves
    int l31 = lane & 31, lh = lane >> 5;
    int nh = w4 >> 1, mq = w4 & 1;
    int base = sb * 128;

    __shared__ unsigned short hs[128 * XPITCH];  // 34816 B
    __shared__ float rsin_s[128];

    if (tid < 128) rsin_s[tid] = rs_in[g * NN + base + tid];

    const unsigned short* Yg = Y1f + (size_t)g * (NN * FH);
    const unsigned short* Ag = AP + (size_t)g * 262144;
    int aoff = (sb * 4 + mq * 2) * 16384 + lh * 256 + l31 * 8;   // Rg0 frags; Rg1 = +16384
    int boff = lh * 1024 + (nh * 64 + l31) * 8;                  // col t=0; t=1 = +256

    f16v a00, a01, a10, a11;
#pragma unroll
    for (int i = 0; i < 16; i++) { a00[i] = 0.f; a01[i] = 0.f; a10[i] = 0.f; a11[i] = 0.f; }

    s8v aF[6][2], bF[6][2];
    auto LD = [&](int buf, int K) {
        aF[buf][0] = *(const s8v*)(Ag + aoff + K * 512);
        aF[buf][1] = *(const s8v*)(Ag + aoff + 16384 + K * 512);
        bF[buf][0] = *(const s8v*)(Yg + boff + K * 2048);
        bF[buf][1] = *(const s8v*)(Yg + boff + 256 + K * 2048);
    };
    LD(0, 0); LD(1, 1); LD(2, 2); LD(3, 3); LD(4, 4); LD(5, 5);
#pragma unroll
    for (int k = 0; k < 32; k++) {
        int cur = k % 6;
        a00 = __builtin_amdgcn_mfma_f32_32x32x16_bf16(aF[cur][0], bF[cur][0], a00, 0, 0, 0);
        a01 = __builtin_amdgcn_mfma_f32_32x32x16_bf16(aF[cur][0], bF[cur][1], a01, 0, 0, 0);
        a10 = __builtin_amdgcn_mfma_f32_32x32x16_bf16(aF[cur][1], bF[cur][0], a10, 0, 0, 0);
        a11 = __builtin_amdgcn_mfma_f32_32x32x16_bf16(aF[cur][1], bF[cur][1], a11, 0, 0, 0);
        if (k + 6 < 32) LD(cur, k + 6);
    }
    __syncthreads();   // rsin visible; agg done

    // ---- conv1 epilogue: h = relu(rs_in*agg + b0) -> hs; C layout (m74) ----
#define EPI1(ACC, Rl, t)                                                        \
    {                                                                           \
        int c = nh * 64 + (t) * 32 + l31;                                       \
        float bv = bias[c];                                                     \
        _Pragma("unroll")                                                       \
        for (int r = 0; r < 16; r++) {                                          \
            int row = (mq * 2 + (Rl)) * 32 + (r & 3) + 8 * (r >> 2) + 4 * lh;   \
            float hv = fmaxf(fmaf(rsin_s[row], (ACC)[r], bv), 0.f);             \
            hs[row * XPITCH + c] = f2bf(hv);                                    \
        }                                                                       \
    }
    EPI1(a00, 0, 0) EPI1(a01, 0, 1) EPI1(a10, 1, 0) EPI1(a11, 1, 1)
#undef EPI1
    __syncthreads();

    // ---- gemm2-32: Y2 = (h @ W1) * rs_out -> Y2P (pack32) ----
    f16v acc2[2][2];
#pragma unroll
    for (int q = 0; q < 2; q++)
#pragma unroll
        for (int t = 0; t < 2; t++)
#pragma unroll
            for (int i = 0; i < 16; i++) acc2[q][t][i] = 0.f;

#pragma unroll
    for (int kk = 0; kk < 8; kk++) {
        s8v a0 = *(const s8v*)&hs[((mq * 2 + 0) * 32 + l31) * XPITCH + kk * 16 + lh * 8];
        s8v a1 = *(const s8v*)&hs[((mq * 2 + 1) * 32 + l31) * XPITCH + kk * 16 + lh * 8];
#pragma unroll
        for (int t = 0; t < 2; t++) {
            int c = nh * 64 + t * 32 + l31;
            s8v bh = *(const s8v*)(W32h + ((size_t)((kk * 2 + lh) * 128 + c)) * 8);
            s8v bl = *(const s8v*)(W32l + ((size_t)((kk * 2 + lh) * 128 + c)) * 8);
            acc2[0][t] = __builtin_amdgcn_mfma_f32_32x32x16_bf16(a0, bh, acc2[0][t], 0, 0, 0);
            acc2[0][t] = __builtin_amdgcn_mfma_f32_32x32x16_bf16(a0, bl, acc2[0][t], 0, 0, 0);
            acc2[1][t] = __builtin_amdgcn_mfma_f32_32x32x16_bf16(a1, bh, acc2[1][t], 0, 0, 0);
            acc2[1][t] = __builtin_amdgcn_mfma_f32_32x32x16_bf16(a1, bl, acc2[1][t], 0, 0, 0);
        }
    }

    // Y2 pack32 store: node n = base + Rgl*32 + 8*rq + 4*lh + (r&3)
    unsigned short* of = Y2f + (size_t)g * (NN * FH);
#pragma unroll
    for (int q = 0; q < 2; q++) {
        int Rgl = mq * 2 + q;
#pragma unroll
        for (int t = 0; t < 2; t++) {
            int c = nh * 64 + t * 32 + l31;
#pragma unroll
            for (int rq = 0; rq < 4; rq++) {
                int n0 = base + Rgl * 32 + 8 * rq + 4 * lh;
                float4 rsv = *(const float4*)(rs_out + (size_t)g * NN + n0);
                int kb = n0 >> 4, lhb = (n0 >> 3) & 1, j0 = n0 & 7;
                us4v v;
                v.x = f2bf(acc2[q][t][rq * 4 + 0] * rsv.x);
                v.y = f2bf(acc2[q][t][rq * 4 + 1] * rsv.y);
                v.z = f2bf(acc2[q][t][rq * 4 + 2] * rsv.z);
                v.w = f2bf(acc2[q][t][rq * 4 + 3] * rsv.w);
                *(us4v*)(of + ((size_t)(kb * 2 + lhb) * 128 + c) * 8 + j0) = v;
            }
        }
    }
}

// ---------------- K4: 64x64/wave fragment GEMM agg + relu + node-sum -> partial ----------------
__global__ __launch_bounds__(256, 2) void k_gather_mean(const unsigned short* __restrict__ Y2f,
                                                        const unsigned short* __restrict__ AP,
                                                        const float* __restrict__ rs_in,
                                                        const float* __restrict__ bias,
                                                        float* __restrict__ partial) {
    int g  = blockIdx.x;
    int sb = blockIdx.y;   // 0..3
    int tid = threadIdx.x;
    int lane = tid & 63, w4 = tid >> 6;
    int l31 = lane & 31, lh = lane >> 5;
    int nh = w4 >> 1, mq = w4 & 1;
    int base = sb * 128;

    __shared__ float red[4 * 2 * 64];   // 2 KB
    __shared__ float rsin_s[128];

    if (tid < 128) rsin_s[tid] = rs_in[g * NN + base + tid];

    const unsigned short* Yg = Y2f + (size_t)g * (NN * FH);
    const unsigned short* Ag = AP + (size_t)g * 262144;
    int aoff = (sb * 4 + mq * 2) * 16384 + lh * 256 + l31 * 8;
    int boff = lh * 1024 + (nh * 64 + l31) * 8;

    f16v a00, a01, a10, a11;
#pragma unroll
    for (int i = 0; i < 16; i++) { a00[i] = 0.f; a01[i] = 0.f; a10[i] = 0.f; a11[i] = 0.f; }

    s8v aF[6][2], bF[6][2];
    auto LD = [&](int buf, int K) {
        aF[buf][0] = *(const s8v*)(Ag + aoff + K * 512);
        aF[buf][1] = *(const s8v*)(Ag + aoff + 16384 + K * 512);
        bF[buf][0] = *(const s8v*)(Yg + boff + K * 2048);
        bF[buf][1] = *(const s8v*)(Yg + boff + 256 + K * 2048);
    };
    LD(0, 0); LD(1, 1); LD(2, 2); LD(3, 3); LD(4, 4); LD(5, 5);
#pragma unroll
    for (int k = 0; k < 32; k++) {
        int cur = k % 6;
        a00 = __builtin_amdgcn_mfma_f32_32x32x16_bf16(aF[cur][0], bF[cur][0], a00, 0, 0, 0);
        a01 = __builtin_amdgcn_mfma_f32_32x32x16_bf16(aF[cur][0], bF[cur][1], a01, 0, 0, 0);
        a10 = __builtin_amdgcn_mfma_f32_32x32x16_bf16(aF[cur][1], bF[cur][0], a10, 0, 0, 0);
        a11 = __builtin_amdgcn_mfma_f32_32x32x16_bf16(aF[cur][1], bF[cur][1], a11, 0, 0, 0);
        if (k + 6 < 32) LD(cur, k + 6);
    }
    __syncthreads();   // rsin visible; agg done

    // ---- epilogue: relu(rs_in*agg + b1) summed over this wave's 64 rows, per col ----
#pragma unroll
    for (int t = 0; t < 2; t++) {
        int c = nh * 64 + t * 32 + l31;
        float bv = bias[c];
        float s = 0.f;
#pragma unroll
        for (int r = 0; r < 16; r++) {
            int row0 = (mq * 2 + 0) * 32 + (r & 3) + 8 * (r >> 2) + 4 * lh;
            int row1 = (mq * 2 + 1) * 32 + (r & 3) + 8 * (r >> 2) + 4 * lh;
            float v0 = (t == 0) ? a00[r] : a01[r];
            float v1 = (t == 0) ? a10[r] : a11[r];
            s += fmaxf(fmaf(rsin_s[row0], v0, bv), 0.f);
            s += fmaxf(fmaf(rsin_s[row1], v1, bv), 0.f);
        }
        red[(w4 * 2 + t) * 64 + lane] = s;
    }
    __syncthreads();
    if (tid < FH) {
        int f = tid;
        int nh2 = f >> 6, t2 = (f >> 5) & 1, cl = f & 31;
        float t = 0.f;
#pragma unroll
        for (int mqq = 0; mqq < 2; mqq++) {
            int w = nh2 * 2 + mqq;
            t += red[(w * 2 + t2) * 64 + cl] + red[(w * 2 + t2) * 64 + cl + 32];
        }
        partial[((size_t)g * 4 + sb) * FH + f] = t;
    }
}

// ---------------- K5: z = (sum partials)/512 @ Wt + bt; BN eval; relu ----------------
__global__ __launch_bounds__(128) void k_head(const float* __restrict__ partial,
                                              const float* __restrict__ Wt,
                                              const float* __restrict__ bt,
                                              const float* __restrict__ gamma,
                                              const float* __restrict__ beta,
                                              const float* __restrict__ rmean,
                                              const float* __restrict__ rvar,
                                              float* __restrict__ out) {
    int g = blockIdx.x;
    int j = threadIdx.x;
    __shared__ float e[FH];
    float acc4 = 0.f;
#pragma unroll
    for (int q = 0; q < 4; q++) acc4 += partial[((size_t)g * 4 + q) * FH + j];
    e[j] = acc4 * (1.0f / (float)NN);
    __syncthreads();
    float acc = bt[j];
#pragma unroll 8
    for (int k = 0; k < FH; k++) acc += e[k] * Wt[(size_t)k * FH + j];
    float z = gamma[j] * (acc - rmean[j]) * rsqrtf(rvar[j] + BN_EPS) + beta[j];
    out[g * FH + j] = fmaxf(z, 0.f);
}

extern "C" void kernel_launch(void* const* d_in, const int* in_sizes, int n_in,
                              void* d_out, int out_size, void* d_ws, size_t ws_size,
                              hipStream_t stream) {
    const float* feats = (const float*)d_in[0];
    const int*   edges = (const int*)d_in[1];
    const float* W0    = (const float*)d_in[2];
    const float* b0    = (const float*)d_in[3];
    const float* W1    = (const float*)d_in[4];
    const float* b1    = (const float*)d_in[5];
    const float* Wt    = (const float*)d_in[6];
    const float* bt    = (const float*)d_in[7];
    const float* gamma = (const float*)d_in[8];
    const float* beta  = (const float*)d_in[9];
    const float* rmean = (const float*)d_in[10];
    const float* rvar  = (const float*)d_in[11];
    float* out = (float*)d_out;

    // workspace layout
    char* w = (char*)d_ws;
    float* rs_out  = (float*)w;   w += sizeof(float) * NG * NN;
    float* rs_in   = (float*)w;   w += sizeof(float) * NG * NN;
    int*   bofs    = (int*)w;     w += sizeof(int) * NG * 33;
    unsigned short* epk = (unsigned short*)w; w += sizeof(unsigned short) * (size_t)NG * NE; // 2 MB
    unsigned short* WP  = (unsigned short*)w; w += sizeof(unsigned short) * 4 * 16384;       // 128 KB
    unsigned short* Y1  = (unsigned short*)w; w += sizeof(unsigned short) * (size_t)NG * NN * FH; // 16 MB
    unsigned short* Y2  = (unsigned short*)w; w += sizeof(unsigned short) * (size_t)NG * NN * FH; // 16 MB
    unsigned short* AP  = (unsigned short*)w; w += sizeof(unsigned short) * (size_t)NG * 262144; // 64 MB
    float* partial = (float*)w;   w += sizeof(float) * NG * 4 * FH;

    unsigned short* WPh0 = WP;
    unsigned short* WPl0 = WP + 16384;
    unsigned short* W32h = WP + 32768;
    unsigned short* W32l = WP + 49152;

    // K1: norms + bucketed packed edges; extra blocks pack W0 (16-frag) and W1 (32-frag)
    k_build<<<NG + 2, 1024, 0, stream>>>(edges, rs_out, rs_in, bofs, epk, W0, W1, WP);

    // K1.5: densify A once -> bf16 MFMA fragments
    k_packA<<<dim3(NG, 4), 512, 0, stream>>>(bofs, epk, AP);

    // K2: conv1 gemm (feats -> Y1, pack32 format)
    k_gemm_f32<<<dim3(NG, 8), 256, 0, stream>>>(feats, WPh0, WPl0, rs_out, Y1);

    // K3: 64x64/wave fragment GEMM agg + gemm2-32 (Y1 -> Y2, pack32)
    k_fused<<<dim3(NG, 4), 256, 0, stream>>>(Y1, AP, rs_in, rs_out, b0, W32h, W32l, Y2);

    // K4: 64x64/wave fragment GEMM agg (conv2) + node-mean -> partial
    k_gather_mean<<<dim3(NG, 4), 256, 0, stream>>>(Y2, AP, rs_in, b1, partial);

    // K5: head
    k_head<<<NG, 128, 0, stream>>>(partial, Wt, bt, gamma, beta, rmean, rvar, out);

    (void)in_sizes; (void)n_in; (void)out_size; (void)ws_size;
}

// Round 10
// 176.681 us; speedup vs baseline: 1.0487x; 1.0211x over previous
//
#include <hip/hip_runtime.h>
#include <hip/hip_bf16.h>

#define NN 512      // nodes per graph
#define NE 8192     // edges per graph
#define NG 128      // graphs (B*G)
#define FH 128      // feature/hidden dim
#define APITCH 68   // A f32 pitch in packA scratch
#define XPITCH 136
#define BN_EPS 1e-5f

typedef __attribute__((ext_vector_type(8))) short s8v;            // 8 bf16 = 4 VGPRs
typedef __attribute__((ext_vector_type(4))) float f4v;            // 16x16 MFMA C/D
typedef __attribute__((ext_vector_type(16))) float f16v;          // 32x32 MFMA C/D
typedef __attribute__((ext_vector_type(4))) unsigned short us4v;  // native ushort4
typedef __attribute__((ext_vector_type(4))) unsigned int u4v;

__device__ inline unsigned short f2bf(float x) {   // RNE fp32 -> bf16 bits
    unsigned u = __float_as_uint(x);
    unsigned r = (u + 0x7fffu + ((u >> 16) & 1u)) >> 16;
    return (unsigned short)r;
}
__device__ inline float bf2f(unsigned short h) { return __uint_as_float(((unsigned)h) << 16); }

// pack hi16(f1):hi16(f0) -> one u32 (exact bf16 for integer-valued floats < 256)
__device__ inline unsigned bfpack(int f1bits, int f0bits) {
    return __builtin_amdgcn_perm((unsigned)f1bits, (unsigned)f0bits, 0x07060302u);
}

// ---------------- K1: degrees + norms + 32-bucket packed edges; extra blocks pack W ----------------
__global__ __launch_bounds__(1024) void k_build(const int* __restrict__ edges,
                                                float* __restrict__ rs_out,
                                                float* __restrict__ rs_in,
                                                int* __restrict__ bofs,
                                                unsigned short* __restrict__ epk,
                                                const float* __restrict__ W0,
                                                const float* __restrict__ W1,
                                                unsigned short* __restrict__ WP) {
    int g = blockIdx.x;
    int tid = threadIdx.x;

    if (g >= NG) {
        int which = g - NG;
        if (which == 0) {
            // W0 -> 16x16 B-frag (WPh0 | WPl0)
            for (int task = tid; task < 2048; task += 1024) {
                int t = task >> 6;            // 0..31  (nt*4+kk)
                int lane = task & 63;
                int nt = t >> 2, kk = t & 3;
                int n = nt * 16 + (lane & 15);
                int k0 = kk * 32 + (lane >> 4) * 8;
                unsigned short* dh = WP + ((size_t)t * 64 + lane) * 8;
                unsigned short* dl = WP + 16384 + ((size_t)t * 64 + lane) * 8;
#pragma unroll
                for (int j = 0; j < 8; j++) {
                    float v = W0[(size_t)(k0 + j) * FH + n];
                    unsigned short h = f2bf(v);
                    dh[j] = h;
                    dl[j] = f2bf(v - bf2f(h));
                }
            }
        } else {
            // W1 -> 32x32 B-frag: ((kk*2+lh)*128 + c)*8 + j holds W1[kk*16 + lh*8 + j][c]
            for (int task = tid; task < 2048; task += 1024) {
                int kk = task >> 8;           // 0..7
                int rem = task & 255;
                int lhp = rem >> 7, c = rem & 127;
                unsigned short* dh = WP + 2 * 16384 + ((size_t)((kk * 2 + lhp) * 128 + c)) * 8;
                unsigned short* dl = WP + 3 * 16384 + ((size_t)((kk * 2 + lhp) * 128 + c)) * 8;
#pragma unroll
                for (int j = 0; j < 8; j++) {
                    float v = W1[(size_t)(kk * 16 + lhp * 8 + j) * FH + c];
                    unsigned short h = f2bf(v);
                    dh[j] = h;
                    dl[j] = f2bf(v - bf2f(h));
                }
            }
        }
        return;
    }

    const int* src = edges + (size_t)g * 2 * NE;
    const int* dst = src + NE;

    __shared__ int degO[NN], degI[NN];
    __shared__ int scanA[1024], scanB[1024];   // [bucket 32][replica 32]
    __shared__ int fill[1024];
    __shared__ unsigned short pk[NE];          // 16 KB packed edges

    for (int i = tid; i < NN; i += 1024) { degO[i] = 0; degI[i] = 0; }
    scanA[tid] = 0;
    __syncthreads();

    int rep = tid & 31;
    for (int u = tid; u < NE / 4; u += 1024) {
        int4 s = ((const int4*)src)[u];
        int4 d = ((const int4*)dst)[u];
        atomicAdd(&degO[s.x], 1); atomicAdd(&degO[s.y], 1);
        atomicAdd(&degO[s.z], 1); atomicAdd(&degO[s.w], 1);
        atomicAdd(&degI[d.x], 1); atomicAdd(&degI[d.y], 1);
        atomicAdd(&degI[d.z], 1); atomicAdd(&degI[d.w], 1);
        atomicAdd(&scanA[((((d.x >> 7) << 3) | (s.x >> 6)) << 5) + rep], 1);
        atomicAdd(&scanA[((((d.y >> 7) << 3) | (s.y >> 6)) << 5) + rep], 1);
        atomicAdd(&scanA[((((d.z >> 7) << 3) | (s.z >> 6)) << 5) + rep], 1);
        atomicAdd(&scanA[((((d.w >> 7) << 3) | (s.w >> 6)) << 5) + rep], 1);
    }
    __syncthreads();

    for (int i = tid; i < NN; i += 1024) {
        rs_out[g * NN + i] = rsqrtf((float)max(degO[i], 1));
        rs_in [g * NN + i] = rsqrtf((float)max(degI[i], 1));
    }

    int* sA = scanA; int* sB = scanB;
    for (int off = 1; off < 1024; off <<= 1) {
        int v = sA[tid];
        if (tid >= off) v += sA[tid - off];
        sB[tid] = v;
        __syncthreads();
        int* t = sA; sA = sB; sB = t;
    }
    int excl = tid ? sA[tid - 1] : 0;
    fill[tid] = excl;
    if ((tid & 31) == 0) bofs[g * 33 + (tid >> 5)] = excl;
    if (tid == 0) bofs[g * 33 + 32] = NE;
    __syncthreads();

    for (int u = tid; u < NE / 4; u += 1024) {
        int4 s = ((const int4*)src)[u];
        int4 d = ((const int4*)dst)[u];
        int c, p;
        c = ((((d.x >> 7) << 3) | (s.x >> 6)) << 5) + rep;
        p = atomicAdd(&fill[c], 1); pk[p] = (unsigned short)(((d.x & 127) << 6) | (s.x & 63));
        c = ((((d.y >> 7) << 3) | (s.y >> 6)) << 5) + rep;
        p = atomicAdd(&fill[c], 1); pk[p] = (unsigned short)(((d.y & 127) << 6) | (s.y & 63));
        c = ((((d.z >> 7) << 3) | (s.z >> 6)) << 5) + rep;
        p = atomicAdd(&fill[c], 1); pk[p] = (unsigned short)(((d.z & 127) << 6) | (s.z & 63));
        c = ((((d.w >> 7) << 3) | (s.w >> 6)) << 5) + rep;
        p = atomicAdd(&fill[c], 1); pk[p] = (unsigned short)(((d.w & 127) << 6) | (s.w & 63));
    }
    __syncthreads();
    ((int4*)(epk + (size_t)g * NE))[tid] = ((const int4*)pk)[tid];
}

// ---------------- K1.5: densify A ONCE -> bf16 MFMA A-fragments in global ----------------
// frag addr (ushort units, per graph): (((Rg*32 + K)*2 + lh)*32 + l31)*8 + j
// holds A[Rg*32 + l31][K*16 + lh*8 + j]
__global__ __launch_bounds__(512) void k_packA(const int* __restrict__ bofs,
                                               const unsigned short* __restrict__ epk,
                                               unsigned short* __restrict__ AP) {
    int g = blockIdx.x, sb = blockIdx.y, tid = threadIdx.x;
    __shared__ float Af[128 * APITCH];    // 34816 B
    __shared__ int bo_s[9];
    const unsigned short* ep = epk + (size_t)g * NE;
    unsigned short* Ag = AP + (size_t)g * 262144;

    if (tid < 9) bo_s[tid] = bofs[g * 33 + sb * 8 + tid];
    __syncthreads();
    int evNext = -1;
    { int e0 = bo_s[0] + tid; if (e0 < bo_s[1]) evNext = (int)ep[e0]; }

    for (int p = 0; p < 8; p++) {
        if (p) __syncthreads();
        float4 z4 = {0.f, 0.f, 0.f, 0.f};
        for (int i = tid; i < 128 * APITCH / 4; i += 512) ((float4*)Af)[i] = z4;
        __syncthreads();
        if (evNext >= 0) atomicAdd(&Af[(evNext >> 6) * APITCH + (evNext & 63)], 1.0f);
        for (int e = bo_s[p] + tid + 512; e < bo_s[p + 1]; e += 512) {
            int v = ep[e];
            atomicAdd(&Af[(v >> 6) * APITCH + (v & 63)], 1.0f);
        }
        __syncthreads();
        if (p < 7) { int e1 = bo_s[p + 1] + tid; evNext = (e1 < bo_s[p + 2]) ? (int)ep[e1] : -1; }
        else evNext = -1;
#pragma unroll
        for (int uu = 0; uu < 2; uu++) {
            int u = tid + uu * 512;
            int l31 = u & 31, lh = (u >> 5) & 1, Kl = (u >> 6) & 3, Rl = (u >> 8) & 3;
            const int4* ap = (const int4*)&Af[(Rl * 32 + l31) * APITCH + Kl * 16 + lh * 8];
            int4 a0 = ap[0], a1 = ap[1];
            u4v cv;
            cv.x = bfpack(a0.y, a0.x);
            cv.y = bfpack(a0.w, a0.z);
            cv.z = bfpack(a1.y, a1.x);
            cv.w = bfpack(a1.w, a1.z);
            int Rg = sb * 4 + Rl, K = p * 4 + Kl;
            *(u4v*)(Ag + (((size_t)(Rg * 32 + K) * 2 + lh) * 32 + l31) * 8) = cv;
        }
    }
}

// ---------------- K2: Y1P = pack32((feats @ W0) * rs_out)  (hi/lo split, 3 MFMA) ----------------
__global__ __launch_bounds__(256) void k_gemm_f32(const float* __restrict__ X,
                                                  const unsigned short* __restrict__ WPh,
                                                  const unsigned short* __restrict__ WPl,
                                                  const float* __restrict__ rs,
                                                  unsigned short* __restrict__ Yf) {
    __shared__ unsigned short xh[64 * XPITCH];   // 17 KB
    __shared__ unsigned short xl[64 * XPITCH];   // 17 KB
    int tid = threadIdx.x;
    int sb = blockIdx.y;
    size_t r0 = (size_t)blockIdx.x * NN + (size_t)sb * 64;

    const float4* Xv = (const float4*)(X + r0 * FH);
#pragma unroll
    for (int i = 0; i < 8; i++) {
        int u = tid + i * 256;                 // 2048 float4 = 64x128
        int row = u >> 5, c4 = (u & 31) * 4;
        float4 v = Xv[u];
        int off = row * XPITCH + c4;
        unsigned short h0 = f2bf(v.x), h1 = f2bf(v.y), h2 = f2bf(v.z), h3 = f2bf(v.w);
        us4v hv, lv;
        hv.x = h0; hv.y = h1; hv.z = h2; hv.w = h3;
        lv.x = f2bf(v.x - bf2f(h0));
        lv.y = f2bf(v.y - bf2f(h1));
        lv.z = f2bf(v.z - bf2f(h2));
        lv.w = f2bf(v.w - bf2f(h3));
        *(us4v*)(xh + off) = hv;
        *(us4v*)(xl + off) = lv;
    }
    __syncthreads();

    int lane = tid & 63, w = tid >> 6;
    int quad = lane >> 4, m = lane & 15;
    int arow = w * 16 + m;

    f4v acc[8];
#pragma unroll
    for (int nt = 0; nt < 8; nt++) acc[nt] = (f4v){0.f, 0.f, 0.f, 0.f};

#pragma unroll
    for (int kk = 0; kk < 4; kk++) {
        s8v ah = *(const s8v*)&xh[arow * XPITCH + kk * 32 + quad * 8];
        s8v al = *(const s8v*)&xl[arow * XPITCH + kk * 32 + quad * 8];
#pragma unroll
        for (int nt = 0; nt < 8; nt++) {
            s8v bh = *(const s8v*)(WPh + ((size_t)(nt * 4 + kk) * 64 + lane) * 8);
            s8v bl = *(const s8v*)(WPl + ((size_t)(nt * 4 + kk) * 64 + lane) * 8);
            acc[nt] = __builtin_amdgcn_mfma_f32_16x16x32_bf16(ah, bh, acc[nt], 0, 0, 0);
            acc[nt] = __builtin_amdgcn_mfma_f32_16x16x32_bf16(al, bh, acc[nt], 0, 0, 0);
            acc[nt] = __builtin_amdgcn_mfma_f32_16x16x32_bf16(ah, bl, acc[nt], 0, 0, 0);
        }
    }

    int orow = w * 16 + quad * 4;
    float4 rsv = *(const float4*)(rs + r0 + orow);
    int kb = sb * 4 + w, h2 = quad >> 1, j0 = (quad & 1) * 4;
    unsigned short* of = Yf + (size_t)blockIdx.x * (NN * FH);
#pragma unroll
    for (int nt = 0; nt < 8; nt++) {
        us4v v;
        v.x = f2bf(acc[nt][0] * rsv.x);
        v.y = f2bf(acc[nt][1] * rsv.y);
        v.z = f2bf(acc[nt][2] * rsv.z);
        v.w = f2bf(acc[nt][3] * rsv.w);
        *(us4v*)(of + ((size_t)(kb * 2 + h2) * 128 + nt * 16 + m) * 8 + j0) = v;
    }
}

// ---------------- K3: whole-graph B in LDS + A-frag stream GEMM agg + gemm2-32 -> Y2P ----------------
// grid (NG,2), 512 thr = 8 waves: (nh = w>>2 col-half, mq = w&3 row-quarter of the 256-row half).
__global__ __launch_bounds__(512) void k_fused(const unsigned short* __restrict__ Y1f,
                                               const unsigned short* __restrict__ AP,
                                               const float* __restrict__ rs_in,
                                               const float* __restrict__ rs_out,
                                               const float* __restrict__ bias,
                                               const unsigned short* __restrict__ W32h,
                                               const unsigned short* __restrict__ W32l,
                                               unsigned short* __restrict__ Y2f) {
    int g  = blockIdx.x;
    int rh = blockIdx.y;   // 0..1 (row half)
    int tid = threadIdx.x;
    int lane = tid & 63, w8 = tid >> 6;
    int l31 = lane & 31, lh = lane >> 5;
    int nh = w8 >> 2, mq = w8 & 3;
    int R0 = rh * 256;

    __shared__ unsigned short Bs[NN * FH];   // 128 KB: whole-graph Y frags; hs aliases after agg
    unsigned short* hs = Bs;                 // 256*XPITCH*2 = 69632 B <= 131072
    __shared__ float rsin_s[256];

    // stage whole-graph Y1P (8192 int4, 16 per thread)
    const int4* Yi4 = (const int4*)(Y1f + (size_t)g * (NN * FH));
    int4* Bi4 = (int4*)Bs;
#pragma unroll
    for (int i = 0; i < 16; i++) Bi4[tid + i * 512] = Yi4[tid + i * 512];
    if (tid < 256) rsin_s[tid] = rs_in[g * NN + R0 + tid];

    const unsigned short* Ag = AP + (size_t)g * 262144;
    int Rg0 = rh * 8 + mq * 2;
    int aoff = Rg0 * 16384 + lh * 256 + l31 * 8;     // Rg1 = +16384
    int boff = lh * 1024 + (nh * 64 + l31) * 8;      // LDS frag base; +256 for +32 cols
    __syncthreads();

    f16v a00, a01, a10, a11;
#pragma unroll
    for (int i = 0; i < 16; i++) { a00[i] = 0.f; a01[i] = 0.f; a10[i] = 0.f; a11[i] = 0.f; }

    s8v aF[6][2];
    auto LD = [&](int buf, int K) {
        aF[buf][0] = *(const s8v*)(Ag + aoff + K * 512);
        aF[buf][1] = *(const s8v*)(Ag + aoff + 16384 + K * 512);
    };
    LD(0, 0); LD(1, 1); LD(2, 2); LD(3, 3); LD(4, 4); LD(5, 5);
#pragma unroll
    for (int k = 0; k < 32; k++) {
        int cur = k % 6;
        s8v b0 = *(const s8v*)&Bs[k * 2048 + boff];
        s8v b1 = *(const s8v*)&Bs[k * 2048 + boff + 256];
        a00 = __builtin_amdgcn_mfma_f32_32x32x16_bf16(aF[cur][0], b0, a00, 0, 0, 0);
        a01 = __builtin_amdgcn_mfma_f32_32x32x16_bf16(aF[cur][0], b1, a01, 0, 0, 0);
        a10 = __builtin_amdgcn_mfma_f32_32x32x16_bf16(aF[cur][1], b0, a10, 0, 0, 0);
        a11 = __builtin_amdgcn_mfma_f32_32x32x16_bf16(aF[cur][1], b1, a11, 0, 0, 0);
        if (k + 6 < 32) LD(cur, k + 6);
    }
    __syncthreads();   // all B reads done; Bs reusable as hs

    // ---- conv1 epilogue: h = relu(rs_in*agg + b0) -> hs; C layout (m74) ----
#pragma unroll
    for (int q = 0; q < 2; q++) {
#pragma unroll
        for (int t = 0; t < 2; t++) {
            int c = nh * 64 + t * 32 + l31;
            float bv = bias[c];
#pragma unroll
            for (int r = 0; r < 16; r++) {
                int lr = mq * 64 + q * 32 + (r & 3) + 8 * (r >> 2) + 4 * lh;
                float v = (q == 0) ? ((t == 0) ? a00[r] : a01[r])
                                   : ((t == 0) ? a10[r] : a11[r]);
                float hv = fmaxf(fmaf(rsin_s[lr], v, bv), 0.f);
                hs[lr * XPITCH + c] = f2bf(hv);
            }
        }
    }
    __syncthreads();

    // ---- gemm2-32: wave w8 owns rows w8*32..+31, all 128 cols ----
    f16v acc2[4];
#pragma unroll
    for (int cb = 0; cb < 4; cb++)
#pragma unroll
        for (int i = 0; i < 16; i++) acc2[cb][i] = 0.f;

#pragma unroll
    for (int kk = 0; kk < 8; kk++) {
        s8v a = *(const s8v*)&hs[(w8 * 32 + l31) * XPITCH + kk * 16 + lh * 8];
#pragma unroll
        for (int cb = 0; cb < 4; cb++) {
            int c = cb * 32 + l31;
            s8v bh = *(const s8v*)(W32h + ((size_t)((kk * 2 + lh) * 128 + c)) * 8);
            s8v bl = *(const s8v*)(W32l + ((size_t)((kk * 2 + lh) * 128 + c)) * 8);
            acc2[cb] = __builtin_amdgcn_mfma_f32_32x32x16_bf16(a, bh, acc2[cb], 0, 0, 0);
            acc2[cb] = __builtin_amdgcn_mfma_f32_32x32x16_bf16(a, bl, acc2[cb], 0, 0, 0);
        }
    }

    // Y2 pack32 store: node n = R0 + w8*32 + 8*rq + 4*lh + (r&3), col c = cb*32 + l31
    unsigned short* of = Y2f + (size_t)g * (NN * FH);
#pragma unroll
    for (int cb = 0; cb < 4; cb++) {
        int c = cb * 32 + l31;
#pragma unroll
        for (int rq = 0; rq < 4; rq++) {
            int n0 = R0 + w8 * 32 + 8 * rq + 4 * lh;
            float4 rsv = *(const float4*)(rs_out + (size_t)g * NN + n0);
            int kb = n0 >> 4, lhb = (n0 >> 3) & 1, j0 = n0 & 7;
            us4v v;
            v.x = f2bf(acc2[cb][rq * 4 + 0] * rsv.x);
            v.y = f2bf(acc2[cb][rq * 4 + 1] * rsv.y);
            v.z = f2bf(acc2[cb][rq * 4 + 2] * rsv.z);
            v.w = f2bf(acc2[cb][rq * 4 + 3] * rsv.w);
            *(us4v*)(of + ((size_t)(kb * 2 + lhb) * 128 + c) * 8 + j0) = v;
        }
    }
}

// ---------------- K4: whole-graph B in LDS + A-frag stream GEMM agg + relu + node-sum -> partial ----------------
__global__ __launch_bounds__(512) void k_gather_mean(const unsigned short* __restrict__ Y2f,
                                                     const unsigned short* __restrict__ AP,
                                                     const float* __restrict__ rs_in,
                                                     const float* __restrict__ bias,
                                                     float* __restrict__ partial) {
    int g  = blockIdx.x;
    int rh = blockIdx.y;   // 0..1
    int tid = threadIdx.x;
    int lane = tid & 63, w8 = tid >> 6;
    int l31 = lane & 31, lh = lane >> 5;
    int nh = w8 >> 2, mq = w8 & 3;
    int R0 = rh * 256;

    __shared__ unsigned short Bs[NN * FH];   // 128 KB; red aliases after agg
    float* red = (float*)Bs;                 // [8][2][64] = 4 KB
    __shared__ float rsin_s[256];

    const int4* Yi4 = (const int4*)(Y2f + (size_t)g * (NN * FH));
    int4* Bi4 = (int4*)Bs;
#pragma unroll
    for (int i = 0; i < 16; i++) Bi4[tid + i * 512] = Yi4[tid + i * 512];
    if (tid < 256) rsin_s[tid] = rs_in[g * NN + R0 + tid];

    const unsigned short* Ag = AP + (size_t)g * 262144;
    int Rg0 = rh * 8 + mq * 2;
    int aoff = Rg0 * 16384 + lh * 256 + l31 * 8;
    int boff = lh * 1024 + (nh * 64 + l31) * 8;
    __syncthreads();

    f16v a00, a01, a10, a11;
#pragma unroll
    for (int i = 0; i < 16; i++) { a00[i] = 0.f; a01[i] = 0.f; a10[i] = 0.f; a11[i] = 0.f; }

    s8v aF[6][2];
    auto LD = [&](int buf, int K) {
        aF[buf][0] = *(const s8v*)(Ag + aoff + K * 512);
        aF[buf][1] = *(const s8v*)(Ag + aoff + 16384 + K * 512);
    };
    LD(0, 0); LD(1, 1); LD(2, 2); LD(3, 3); LD(4, 4); LD(5, 5);
#pragma unroll
    for (int k = 0; k < 32; k++) {
        int cur = k % 6;
        s8v b0 = *(const s8v*)&Bs[k * 2048 + boff];
        s8v b1 = *(const s8v*)&Bs[k * 2048 + boff + 256];
        a00 = __builtin_amdgcn_mfma_f32_32x32x16_bf16(aF[cur][0], b0, a00, 0, 0, 0);
        a01 = __builtin_amdgcn_mfma_f32_32x32x16_bf16(aF[cur][0], b1, a01, 0, 0, 0);
        a10 = __builtin_amdgcn_mfma_f32_32x32x16_bf16(aF[cur][1], b0, a10, 0, 0, 0);
        a11 = __builtin_amdgcn_mfma_f32_32x32x16_bf16(aF[cur][1], b1, a11, 0, 0, 0);
        if (k + 6 < 32) LD(cur, k + 6);
    }
    __syncthreads();   // all B reads done; Bs reusable as red

    // ---- epilogue: relu(rs_in*agg + b1) summed over this wave's 64 rows, per col ----
#pragma unroll
    for (int t = 0; t < 2; t++) {
        int c = nh * 64 + t * 32 + l31;
        float bv = bias[c];
        float s = 0.f;
#pragma unroll
        for (int r = 0; r < 16; r++) {
            int lr0 = mq * 64 + 0  + (r & 3) + 8 * (r >> 2) + 4 * lh;
            int lr1 = mq * 64 + 32 + (r & 3) + 8 * (r >> 2) + 4 * lh;
            float v0 = (t == 0) ? a00[r] : a01[r];
            float v1 = (t == 0) ? a10[r] : a11[r];
            s += fmaxf(fmaf(rsin_s[lr0], v0, bv), 0.f);
            s += fmaxf(fmaf(rsin_s[lr1], v1, bv), 0.f);
        }
        red[(w8 * 2 + t) * 64 + lane] = s;
    }
    __syncthreads();
    if (tid < FH) {
        int f = tid;
        int nh2 = f >> 6, t2 = (f >> 5) & 1, cl = f & 31;
        float t = 0.f;
#pragma unroll
        for (int mqq = 0; mqq < 4; mqq++) {
            int w = nh2 * 4 + mqq;
            t += red[(w * 2 + t2) * 64 + cl] + red[(w * 2 + t2) * 64 + cl + 32];
        }
        partial[((size_t)g * 2 + rh) * FH + f] = t;
    }
}

// ---------------- K5: z = (sum partials)/512 @ Wt + bt; BN eval; relu ----------------
__global__ __launch_bounds__(128) void k_head(const float* __restrict__ partial,
                                              const float* __restrict__ Wt,
                                              const float* __restrict__ bt,
                                              const float* __restrict__ gamma,
                                              const float* __restrict__ beta,
                                              const float* __restrict__ rmean,
                                              const float* __restrict__ rvar,
                                              float* __restrict__ out) {
    int g = blockIdx.x;
    int j = threadIdx.x;
    __shared__ float e[FH];
    float acc2 = partial[((size_t)g * 2 + 0) * FH + j] + partial[((size_t)g * 2 + 1) * FH + j];
    e[j] = acc2 * (1.0f / (float)NN);
    __syncthreads();
    float acc = bt[j];
#pragma unroll 8
    for (int k = 0; k < FH; k++) acc += e[k] * Wt[(size_t)k * FH + j];
    float z = gamma[j] * (acc - rmean[j]) * rsqrtf(rvar[j] + BN_EPS) + beta[j];
    out[g * FH + j] = fmaxf(z, 0.f);
}

extern "C" void kernel_launch(void* const* d_in, const int* in_sizes, int n_in,
                              void* d_out, int out_size, void* d_ws, size_t ws_size,
                              hipStream_t stream) {
    const float* feats = (const float*)d_in[0];
    const int*   edges = (const int*)d_in[1];
    const float* W0    = (const float*)d_in[2];
    const float* b0    = (const float*)d_in[3];
    const float* W1    = (const float*)d_in[4];
    const float* b1    = (const float*)d_in[5];
    const float* Wt    = (const float*)d_in[6];
    const float* bt    = (const float*)d_in[7];
    const float* gamma = (const float*)d_in[8];
    const float* beta  = (const float*)d_in[9];
    const float* rmean = (const float*)d_in[10];
    const float* rvar  = (const float*)d_in[11];
    float* out = (float*)d_out;

    // workspace layout
    char* w = (char*)d_ws;
    float* rs_out  = (float*)w;   w += sizeof(float) * NG * NN;
    float* rs_in   = (float*)w;   w += sizeof(float) * NG * NN;
    int*   bofs    = (int*)w;     w += sizeof(int) * NG * 33;
    unsigned short* epk = (unsigned short*)w; w += sizeof(unsigned short) * (size_t)NG * NE; // 2 MB
    unsigned short* WP  = (unsigned short*)w; w += sizeof(unsigned short) * 4 * 16384;       // 128 KB
    unsigned short* Y1  = (unsigned short*)w; w += sizeof(unsigned short) * (size_t)NG * NN * FH; // 16 MB
    unsigned short* Y2  = (unsigned short*)w; w += sizeof(unsigned short) * (size_t)NG * NN * FH; // 16 MB
    unsigned short* AP  = (unsigned short*)w; w += sizeof(unsigned short) * (size_t)NG * 262144; // 64 MB
    float* partial = (float*)w;   w += sizeof(float) * NG * 2 * FH;

    unsigned short* WPh0 = WP;
    unsigned short* WPl0 = WP + 16384;
    unsigned short* W32h = WP + 32768;
    unsigned short* W32l = WP + 49152;

    // K1: norms + bucketed packed edges; extra blocks pack W0 (16-frag) and W1 (32-frag)
    k_build<<<NG + 2, 1024, 0, stream>>>(edges, rs_out, rs_in, bofs, epk, W0, W1, WP);

    // K1.5: densify A once -> bf16 MFMA fragments
    k_packA<<<dim3(NG, 4), 512, 0, stream>>>(bofs, epk, AP);

    // K2: conv1 gemm (feats -> Y1, pack32 format)
    k_gemm_f32<<<dim3(NG, 8), 256, 0, stream>>>(feats, WPh0, WPl0, rs_out, Y1);

    // K3: whole-graph-B-in-LDS fragment GEMM agg + gemm2-32 (Y1 -> Y2, pack32)
    k_fused<<<dim3(NG, 2), 512, 0, stream>>>(Y1, AP, rs_in, rs_out, b0, W32h, W32l, Y2);

    // K4: whole-graph-B-in-LDS fragment GEMM agg (conv2) + node-mean -> partial
    k_gather_mean<<<dim3(NG, 2), 512, 0, stream>>>(Y2, AP, rs_in, b1, partial);

    // K5: head
    k_head<<<NG, 128, 0, stream>>>(partial, Wt, bt, gamma, beta, rmean, rvar, out);

    (void)in_sizes; (void)n_in; (void)out_size; (void)ws_size;
}